// Round 1
// baseline (16473.302 us; speedup 1.0000x reference)
//
#include <hip/hip_runtime.h>
#include <math.h>

// ---------------------------------------------------------------------------
// AdvancedMixConsole: 64 tracks x 131072 samples.
//   gain -> 6 biquads (chunk-parallel linear recurrence, 12-dim state)
//        -> compressor (parallel g; serial max-affine smoother, pair-composed)
//        -> pan/mix (parallel).
// ---------------------------------------------------------------------------

#define S_LEN 131072
#define NTR   64
#define CCH   128          // chunks
#define LCH   1024         // samples per chunk
#define NPAIR 65536        // S/2
#define PPC   512          // pairs per chunk

typedef float v2f __attribute__((ext_vector_type(2)));

// ws offsets in floats (total ~118.3 MB)
#define OFF_Y    0ull               // [NPAIR][64][2]  {y_even, y_odd}
#define OFF_CP   8388608ull         // [NPAIR][64][4]  {C1,C2,C3,g_even}
#define OFF_QO   25165824ull        // [NPAIR][64]     q at odd samples
#define OFF_COEF 29360128ull        // [64][32]  biquad coeffs (b0,b1,b2,a1,a2)x6
#define OFF_COMP 29362176ull        // [64][16]  compressor/pan constants
#define OFF_A    29363200ull        // [64][144] cascade transition matrix
#define OFF_M    29372416ull        // [64][144] A^LCH
#define OFF_F    29381632ull        // [64][128][12] zero-init chunk finals
#define OFF_Z    29479936ull        // [64][128][12] chunk init states

// ---------------------------------------------------------------------------
__global__ __launch_bounds__(64) void k_setup(const float* __restrict__ mp,
                                              float* __restrict__ ws) {
  int n = threadIdx.x;
  if (n >= NTR) return;
  const float* p = mp + n * 26;
  auto dn = [&](int i, double lo, double hi) { return (double)p[i] * (hi - lo) + lo; };

  double gain_db = dn(0, -24.0, 24.0);
  double glin = pow(10.0, gain_db / 20.0);
  const double nyq = 21050.0;  // 44100//2 - 1000

  double fg[6] = {dn(1,-24,24), dn(4,-24,24), dn(7,-24,24), dn(10,-24,24), dn(13,-24,24), dn(16,-24,24)};
  double ff[6] = {dn(2,20,2000), dn(5,80,2000), dn(8,2000,8000), dn(11,8000,12000), dn(14,12000,nyq), dn(17,6000,nyq)};
  double fq[6] = {dn(3,0.1,5), dn(6,0.1,5), dn(9,0.1,5), dn(12,0.1,5), dn(15,0.1,5), dn(18,0.1,5)};

  double B0[6], B1[6], B2[6], A1[6], A2[6];
  for (int k = 0; k < 6; k++) {
    double A  = pow(10.0, fg[k] / 40.0);
    double w0 = 2.0 * M_PI * ff[k] / 44100.0;
    double cw = cos(w0), sw = sin(w0);
    double al = sw / (2.0 * fq[k]);
    double sA = sqrt(A);
    double b0, b1, b2, a0, a1, a2;
    if (k == 0) {           // low shelf
      b0 = A*((A+1)-(A-1)*cw + 2*sA*al);
      b1 = 2*A*((A-1)-(A+1)*cw);
      b2 = A*((A+1)-(A-1)*cw - 2*sA*al);
      a0 = (A+1)+(A-1)*cw + 2*sA*al;
      a1 = -2*((A-1)+(A+1)*cw);
      a2 = (A+1)+(A-1)*cw - 2*sA*al;
    } else if (k == 5) {    // high shelf
      b0 = A*((A+1)+(A-1)*cw + 2*sA*al);
      b1 = -2*A*((A-1)+(A+1)*cw);
      b2 = A*((A+1)+(A-1)*cw - 2*sA*al);
      a0 = (A+1)-(A-1)*cw + 2*sA*al;
      a1 = 2*((A-1)-(A+1)*cw);
      a2 = (A+1)-(A-1)*cw - 2*sA*al;
    } else {                // peak
      b0 = 1 + al*A; b1 = -2*cw; b2 = 1 - al*A;
      a0 = 1 + al/A; a1 = -2*cw; a2 = 1 - al/A;
    }
    B0[k] = b0/a0; B1[k] = b1/a0; B2[k] = b2/a0; A1[k] = a1/a0; A2[k] = a2/a0;
  }
  // fold input gain into stage-0 numerator
  B0[0] *= glin; B1[0] *= glin; B2[0] *= glin;

  float* cf = ws + OFF_COEF + n * 32;
  for (int k = 0; k < 6; k++) {
    cf[k*5+0] = (float)B0[k]; cf[k*5+1] = (float)B1[k]; cf[k*5+2] = (float)B2[k];
    cf[k*5+3] = (float)A1[k]; cf[k*5+4] = (float)A2[k];
  }

  // compressor + pan constants
  double T = dn(19,-60,0), R = dn(20,1,10), atk = dn(21,1,1000), rel = dn(22,1,1000);
  double Kn = dn(23,3,24), mk = dn(24,0,24);
  double a_a = exp(-1.0 / (44100.0 * atk * 0.001));
  double a_r = exp(-1.0 / (44100.0 * rel * 0.001));
  double s   = (a_a < a_r) ? 1.0 : -1.0;     // q = s*p makes the recurrence pure-max
  double kca = s * (1.0 - a_a), kcr = s * (1.0 - a_r);
  double invR = 1.0 / R;
  const double K10 = 0.16609640474436813;    // log2(10)/20
  double theta = (double)p[25] * (M_PI / 2.0);

  float* cm = ws + OFF_COMP + n * 16;
  cm[0] = (float)a_a;  cm[1] = (float)a_r;  cm[2] = (float)kca; cm[3] = (float)kcr;
  cm[4] = (float)T;    cm[5] = (float)(Kn * 0.5);
  cm[6] = (float)(1.0 - invR);
  cm[7] = (float)((1.0 - invR) / (2.0 * Kn));
  cm[8] = (float)(mk * K10);   cm[9] = (float)(s * K10);
  cm[10] = (float)cos(theta);  cm[11] = (float)sin(theta);
  cm[12] = (float)(a_a * kcr); cm[13] = (float)(a_r * kca);
  cm[14] = 0.f; cm[15] = 0.f;

  // homogeneous (x=0) cascade transition matrix, state = [s1_1,s2_1,...,s1_6,s2_6]
  double Am[12][12], yv[12], ny[12];
  for (int r = 0; r < 12; r++) { yv[r] = 0; for (int c = 0; c < 12; c++) Am[r][c] = 0; }
  for (int k = 0; k < 6; k++) {
    for (int c = 0; c < 12; c++) ny[c] = B0[k] * yv[c];
    ny[2*k] += 1.0;                                  // y_k = b0*y_{k-1} + s1_k
    for (int c = 0; c < 12; c++) Am[2*k][c]   = B1[k]*yv[c] - A1[k]*ny[c];
    Am[2*k][2*k+1] += 1.0;                           // + s2_k
    for (int c = 0; c < 12; c++) Am[2*k+1][c] = B2[k]*yv[c] - A2[k]*ny[c];
    for (int c = 0; c < 12; c++) yv[c] = ny[c];
  }
  float* Aw = ws + OFF_A + n * 144;
  for (int r = 0; r < 12; r++)
    for (int c = 0; c < 12; c++) Aw[r*12+c] = (float)Am[r][c];
}

// ---------------------------------------------------------------------------
__global__ __launch_bounds__(192) void k_matpow(float* __restrict__ ws) {
  __shared__ float As[144];
  int n = blockIdx.x, t = threadIdx.x;
  int r = t / 12, c = t % 12;
  if (t < 144) As[t] = ws[OFF_A + (size_t)n*144 + t];
  __syncthreads();
  for (int it = 0; it < 10; ++it) {   // A^(2^10) = A^LCH
    float acc = 0.f;
    if (t < 144) {
      #pragma unroll
      for (int k = 0; k < 12; k++) acc += As[r*12+k] * As[k*12+c];
    }
    __syncthreads();
    if (t < 144) As[t] = acc;
    __syncthreads();
  }
  if (t < 144) ws[OFF_M + (size_t)n*144 + t] = As[t];
}

// ---------------------------------------------------------------------------
__device__ __forceinline__ void load_coefs(const float* cf, float* b0, v2f* bb, v2f* naa) {
  #pragma unroll
  for (int k = 0; k < 6; k++) {
    b0[k]  = cf[k*5+0];
    bb[k]  = (v2f){cf[k*5+1], cf[k*5+2]};
    naa[k] = (v2f){-cf[k*5+3], -cf[k*5+4]};
  }
}

__device__ __forceinline__ float cascade_step(float x, float* b0, v2f* bb, v2f* naa, v2f* st) {
  #pragma unroll
  for (int k = 0; k < 6; k++) {
    float y  = fmaf(b0[k], x, st[k].x);
    v2f upd  = __builtin_elementwise_fma(bb[k], (v2f){x, x}, (v2f){st[k].y, 0.f});
    st[k]    = __builtin_elementwise_fma(naa[k], (v2f){y, y}, upd);
    x = y;
  }
  return x;
}

// phase 1: zero-init chunk finals
__global__ __launch_bounds__(64) void k_phase1(const float* __restrict__ tracks,
                                               float* __restrict__ ws) {
  int j = blockIdx.x, n = threadIdx.x;
  float b0[6]; v2f bb[6], naa[6];
  load_coefs(ws + OFF_COEF + n*32, b0, bb, naa);
  v2f st[6];
  #pragma unroll
  for (int k = 0; k < 6; k++) st[k] = (v2f){0.f, 0.f};
  const float4* xp = (const float4*)(tracks + (size_t)n*S_LEN + (size_t)j*LCH);
  for (int i4 = 0; i4 < LCH/4; ++i4) {
    float4 xq = xp[i4];
    float xs[4] = {xq.x, xq.y, xq.z, xq.w};
    #pragma unroll
    for (int u = 0; u < 4; u++) (void)cascade_step(xs[u], b0, bb, naa, st);
  }
  float* f = ws + OFF_F + (size_t)n*(CCH*12) + (size_t)j*12;
  #pragma unroll
  for (int k = 0; k < 6; k++) { f[2*k] = st[k].x; f[2*k+1] = st[k].y; }
}

// serial scan of chunk-boundary states: z_{j+1} = M z_j + f_j
__global__ __launch_bounds__(64) void k_scanz(float* __restrict__ ws) {
  int n = threadIdx.x;
  float M[144];
  #pragma unroll
  for (int i = 0; i < 144; i++) M[i] = ws[OFF_M + (size_t)n*144 + i];
  float z[12];
  #pragma unroll
  for (int r = 0; r < 12; r++) z[r] = 0.f;
  const float* fb = ws + OFF_F + (size_t)n*(CCH*12);
  float*       zb = ws + OFF_Z + (size_t)n*(CCH*12);
  for (int j = 0; j < CCH; j++) {
    #pragma unroll
    for (int r = 0; r < 12; r++) zb[j*12+r] = z[r];
    float nz[12];
    #pragma unroll
    for (int r = 0; r < 12; r++) {
      float acc = fb[j*12+r];
      #pragma unroll
      for (int c = 0; c < 12; c++) acc = fmaf(M[r*12+c], z[c], acc);
      nz[r] = acc;
    }
    #pragma unroll
    for (int r = 0; r < 12; r++) z[r] = nz[r];
  }
}

// phase 3: correct-init EQ, compressor static gain g, pair-composed intercepts
__global__ __launch_bounds__(64) void k_phase3(const float* __restrict__ tracks,
                                               float* __restrict__ ws) {
  int j = blockIdx.x, n = threadIdx.x;
  float b0[6]; v2f bb[6], naa[6];
  load_coefs(ws + OFF_COEF + n*32, b0, bb, naa);
  const float* cm = ws + OFF_COMP + n*16;
  float a_a = cm[0], a_r = cm[1], kca = cm[2], kcr = cm[3];
  float T = cm[4], hK = cm[5], cg1 = cm[6], cg2 = cm[7];
  float u1 = cm[12], u2 = cm[13];
  v2f st[6];
  const float* zp = ws + OFF_Z + (size_t)n*(CCH*12) + (size_t)j*12;
  #pragma unroll
  for (int k = 0; k < 6; k++) st[k] = (v2f){zp[2*k], zp[2*k+1]};

  const float4* xp  = (const float4*)(tracks + (size_t)n*S_LEN + (size_t)j*LCH);
  float4* cpq = (float4*)(ws + OFF_CP) + (size_t)j*PPC*64;
  float2* yb  = (float2*)(ws + OFF_Y)  + (size_t)j*PPC*64;

  for (int i4 = 0; i4 < LCH/4; ++i4) {      // 2 pairs per iteration
    float4 xq = xp[i4];
    float xs[4] = {xq.x, xq.y, xq.z, xq.w};
    float ys[4], gv[4];
    #pragma unroll
    for (int u = 0; u < 4; u++) {
      float y = cascade_step(xs[u], b0, bb, naa, st);
      ys[u] = y;
      float v   = fabsf(y) + 1e-8f;
      float xdb = 6.020599913279624f * __log2f(v);   // 20*log10
      float d   = xdb - T;
      float dk  = d + hK;
      float g   = (d > hK) ? (cg1 * d) : (cg2 * dk * dk);
      g = (d < -hK) ? 0.f : g;
      gv[u] = g;
    }
    #pragma unroll
    for (int pp = 0; pp < 2; ++pp) {
      float ge = gv[2*pp], go = gv[2*pp+1];
      float C1 = kca * fmaf(a_a, ge, go);
      float C3 = kcr * fmaf(a_r, ge, go);
      float C2 = fmaxf(fmaf(u1, ge, kca*go), fmaf(u2, ge, kcr*go));
      int m = i4*2 + pp;
      cpq[(size_t)m*64 + n] = make_float4(C1, C2, C3, ge);
      yb [(size_t)m*64 + n] = make_float2(ys[2*pp], ys[2*pp+1]);
    }
  }
}

// serial max-affine smoother, odd samples only (pair-composed)
__global__ __launch_bounds__(64) void k_smooth(float* __restrict__ ws) {
  int n = threadIdx.x;
  const float* cm = ws + OFF_COMP + n*16;
  float a_a = cm[0], a_r = cm[1];
  float aa2 = a_a*a_a, aar = a_a*a_r, ar2 = a_r*a_r;
  const float4* cp = (const float4*)(ws + OFF_CP);
  float* qo = ws + OFF_QO;
  float q = 0.f;
  #pragma unroll 8
  for (int m = 0; m < NPAIR; ++m) {
    float4 c = cp[(size_t)m*64 + n];
    q = fmaxf(fmaxf(fmaf(aa2, q, c.x), fmaf(aar, q, c.y)), fmaf(ar2, q, c.z));
    qo[(size_t)m*64 + n] = q;
  }
}

// even-sample reconstruction + makeup gain + pan + 16-track mix
__global__ __launch_bounds__(256) void k_mix(const float* __restrict__ ws,
                                             float* __restrict__ out) {
  int b  = threadIdx.x & 3;
  int kk = blockIdx.x * 64 + (threadIdx.x >> 2);
  const float*  qo   = ws + OFF_QO;
  const float4* cp   = (const float4*)(ws + OFF_CP);
  const float2* yb   = (const float2*)(ws + OFF_Y);
  const float4* cmp4 = (const float4*)(ws + OFF_COMP);
  float accLe = 0, accRe = 0, accLo = 0, accRo = 0;
  int n0 = b * 16;
  int kp = (kk > 0) ? (kk - 1) : 0;
  #pragma unroll
  for (int t = 0; t < 16; t++) {
    int n = n0 + t;
    float4 ca = cmp4[n*4 + 0];              // a_a, a_r, kca, kcr
    float4 cc = cmp4[n*4 + 2];              // mka, sfac, cos, sin
    float qodd  = qo[(size_t)kk*64 + n];
    float qprev = qo[(size_t)kp*64 + n];
    qprev = (kk > 0) ? qprev : 0.f;
    float ge = cp[(size_t)kk*64 + n].w;
    float2 y2 = yb[(size_t)kk*64 + n];
    float qe  = fmaxf(fmaf(ca.x, qprev, ca.z*ge), fmaf(ca.y, qprev, ca.w*ge));
    float gle = exp2f(fmaf(-cc.y, qe,   cc.x));
    float glo = exp2f(fmaf(-cc.y, qodd, cc.x));
    float te = y2.x * gle, to = y2.y * glo;
    accLe = fmaf(cc.z, te, accLe); accRe = fmaf(cc.w, te, accRe);
    accLo = fmaf(cc.z, to, accLo); accRo = fmaf(cc.w, to, accRo);
  }
  float2* o = (float2*)out;
  o[(size_t)(b*2 + 0)*(S_LEN/2) + kk] = make_float2(accLe, accLo);
  o[(size_t)(b*2 + 1)*(S_LEN/2) + kk] = make_float2(accRe, accRo);
}

// ---------------------------------------------------------------------------
extern "C" void kernel_launch(void* const* d_in, const int* in_sizes, int n_in,
                              void* d_out, int out_size, void* d_ws, size_t ws_size,
                              hipStream_t stream) {
  const float* tracks = (const float*)d_in[0];
  const float* mp     = (const float*)d_in[1];
  float* ws  = (float*)d_ws;
  float* out = (float*)d_out;

  hipLaunchKernelGGL(k_setup,  dim3(1),    dim3(64),  0, stream, mp, ws);
  hipLaunchKernelGGL(k_matpow, dim3(64),   dim3(192), 0, stream, ws);
  hipLaunchKernelGGL(k_phase1, dim3(CCH),  dim3(64),  0, stream, tracks, ws);
  hipLaunchKernelGGL(k_scanz,  dim3(1),    dim3(64),  0, stream, ws);
  hipLaunchKernelGGL(k_phase3, dim3(CCH),  dim3(64),  0, stream, tracks, ws);
  hipLaunchKernelGGL(k_smooth, dim3(1),    dim3(64),  0, stream, ws);
  hipLaunchKernelGGL(k_mix,    dim3(NPAIR/64), dim3(256), 0, stream, ws, out);
}

// Round 3
// 1645.516 us; speedup vs baseline: 10.0110x; 10.0110x over previous
//
#include <hip/hip_runtime.h>
#include <math.h>

// ---------------------------------------------------------------------------
// AdvancedMixConsole: 64 tracks x 131072 samples.
//   gain -> 6 biquads (chunk-parallel linear recurrence, 12-dim state)
//        -> compressor (parallel g; serial max-affine smoother, pair-composed,
//           one wave PER TRACK across 64 CUs)
//        -> pan/mix (parallel).
// ---------------------------------------------------------------------------

#define S_LEN 131072
#define NTR   64
#define CCH   128          // chunks
#define LCH   1024         // samples per chunk
#define NPAIR 65536        // S/2
#define PPC   512          // pairs per chunk

typedef float v2f __attribute__((ext_vector_type(2)));

// ws offsets in floats (total ~118.3 MB)
#define OFF_Y    0ull               // [NPAIR][64][2]  {y_even, y_odd}
#define OFF_CP   8388608ull         // [NPAIR][64][4]  {C1,C2,C3,g_even}
#define OFF_QO   25165824ull        // [64][NPAIR]     q at odd samples (track-major)
#define OFF_COEF 29360128ull        // [64][32]  biquad coeffs (b0,b1,b2,a1,a2)x6
#define OFF_COMP 29362176ull        // [64][16]  compressor/pan constants
#define OFF_A    29363200ull        // [64][144] cascade transition matrix
#define OFF_M    29372416ull        // [64][144] A^LCH
#define OFF_F    29381632ull        // [64][128][12] zero-init chunk finals
#define OFF_Z    29479936ull        // [64][128][12] chunk init states

// ---------------------------------------------------------------------------
__global__ __launch_bounds__(64) void k_setup(const float* __restrict__ mp,
                                              float* __restrict__ ws) {
  int n = threadIdx.x;
  if (n >= NTR) return;
  const float* p = mp + n * 26;
  auto dn = [&](int i, double lo, double hi) { return (double)p[i] * (hi - lo) + lo; };

  double gain_db = dn(0, -24.0, 24.0);
  double glin = pow(10.0, gain_db / 20.0);
  const double nyq = 21050.0;  // 44100//2 - 1000

  double fg[6] = {dn(1,-24,24), dn(4,-24,24), dn(7,-24,24), dn(10,-24,24), dn(13,-24,24), dn(16,-24,24)};
  double ff[6] = {dn(2,20,2000), dn(5,80,2000), dn(8,2000,8000), dn(11,8000,12000), dn(14,12000,nyq), dn(17,6000,nyq)};
  double fq[6] = {dn(3,0.1,5), dn(6,0.1,5), dn(9,0.1,5), dn(12,0.1,5), dn(15,0.1,5), dn(18,0.1,5)};

  double B0[6], B1[6], B2[6], A1[6], A2[6];
  for (int k = 0; k < 6; k++) {
    double A  = pow(10.0, fg[k] / 40.0);
    double w0 = 2.0 * M_PI * ff[k] / 44100.0;
    double cw = cos(w0), sw = sin(w0);
    double al = sw / (2.0 * fq[k]);
    double sA = sqrt(A);
    double b0, b1, b2, a0, a1, a2;
    if (k == 0) {           // low shelf
      b0 = A*((A+1)-(A-1)*cw + 2*sA*al);
      b1 = 2*A*((A-1)-(A+1)*cw);
      b2 = A*((A+1)-(A-1)*cw - 2*sA*al);
      a0 = (A+1)+(A-1)*cw + 2*sA*al;
      a1 = -2*((A-1)+(A+1)*cw);
      a2 = (A+1)+(A-1)*cw - 2*sA*al;
    } else if (k == 5) {    // high shelf
      b0 = A*((A+1)+(A-1)*cw + 2*sA*al);
      b1 = -2*A*((A-1)+(A+1)*cw);
      b2 = A*((A+1)+(A-1)*cw - 2*sA*al);
      a0 = (A+1)-(A-1)*cw + 2*sA*al;
      a1 = 2*((A-1)-(A+1)*cw);
      a2 = (A+1)-(A-1)*cw - 2*sA*al;
    } else {                // peak
      b0 = 1 + al*A; b1 = -2*cw; b2 = 1 - al*A;
      a0 = 1 + al/A; a1 = -2*cw; a2 = 1 - al/A;
    }
    B0[k] = b0/a0; B1[k] = b1/a0; B2[k] = b2/a0; A1[k] = a1/a0; A2[k] = a2/a0;
  }
  // fold input gain into stage-0 numerator
  B0[0] *= glin; B1[0] *= glin; B2[0] *= glin;

  float* cf = ws + OFF_COEF + n * 32;
  for (int k = 0; k < 6; k++) {
    cf[k*5+0] = (float)B0[k]; cf[k*5+1] = (float)B1[k]; cf[k*5+2] = (float)B2[k];
    cf[k*5+3] = (float)A1[k]; cf[k*5+4] = (float)A2[k];
  }

  // compressor + pan constants
  double T = dn(19,-60,0), R = dn(20,1,10), atk = dn(21,1,1000), rel = dn(22,1,1000);
  double Kn = dn(23,3,24), mk = dn(24,0,24);
  double a_a = exp(-1.0 / (44100.0 * atk * 0.001));
  double a_r = exp(-1.0 / (44100.0 * rel * 0.001));
  double s   = (a_a < a_r) ? 1.0 : -1.0;     // q = s*p makes the recurrence pure-max
  double kca = s * (1.0 - a_a), kcr = s * (1.0 - a_r);
  double invR = 1.0 / R;
  const double K10 = 0.16609640474436813;    // log2(10)/20
  double theta = (double)p[25] * (M_PI / 2.0);

  float* cm = ws + OFF_COMP + n * 16;
  cm[0] = (float)a_a;  cm[1] = (float)a_r;  cm[2] = (float)kca; cm[3] = (float)kcr;
  cm[4] = (float)T;    cm[5] = (float)(Kn * 0.5);
  cm[6] = (float)(1.0 - invR);
  cm[7] = (float)((1.0 - invR) / (2.0 * Kn));
  cm[8] = (float)(mk * K10);   cm[9] = (float)(s * K10);
  cm[10] = (float)cos(theta);  cm[11] = (float)sin(theta);
  cm[12] = (float)(a_a * kcr); cm[13] = (float)(a_r * kca);
  cm[14] = 0.f; cm[15] = 0.f;

  // homogeneous (x=0) cascade transition matrix, state = [s1_1,s2_1,...,s1_6,s2_6]
  double Am[12][12], yv[12], ny[12];
  for (int r = 0; r < 12; r++) { yv[r] = 0; for (int c = 0; c < 12; c++) Am[r][c] = 0; }
  for (int k = 0; k < 6; k++) {
    for (int c = 0; c < 12; c++) ny[c] = B0[k] * yv[c];
    ny[2*k] += 1.0;                                  // y_k = b0*y_{k-1} + s1_k
    for (int c = 0; c < 12; c++) Am[2*k][c]   = B1[k]*yv[c] - A1[k]*ny[c];
    Am[2*k][2*k+1] += 1.0;                           // + s2_k
    for (int c = 0; c < 12; c++) Am[2*k+1][c] = B2[k]*yv[c] - A2[k]*ny[c];
    for (int c = 0; c < 12; c++) yv[c] = ny[c];
  }
  float* Aw = ws + OFF_A + n * 144;
  for (int r = 0; r < 12; r++)
    for (int c = 0; c < 12; c++) Aw[r*12+c] = (float)Am[r][c];
}

// ---------------------------------------------------------------------------
__global__ __launch_bounds__(192) void k_matpow(float* __restrict__ ws) {
  __shared__ float As[144];
  int n = blockIdx.x, t = threadIdx.x;
  int r = t / 12, c = t % 12;
  if (t < 144) As[t] = ws[OFF_A + (size_t)n*144 + t];
  __syncthreads();
  for (int it = 0; it < 10; ++it) {   // A^(2^10) = A^LCH
    float acc = 0.f;
    if (t < 144) {
      #pragma unroll
      for (int k = 0; k < 12; k++) acc += As[r*12+k] * As[k*12+c];
    }
    __syncthreads();
    if (t < 144) As[t] = acc;
    __syncthreads();
  }
  if (t < 144) ws[OFF_M + (size_t)n*144 + t] = As[t];
}

// ---------------------------------------------------------------------------
__device__ __forceinline__ void load_coefs(const float* cf, float* b0, v2f* bb, v2f* naa) {
  #pragma unroll
  for (int k = 0; k < 6; k++) {
    b0[k]  = cf[k*5+0];
    bb[k]  = (v2f){cf[k*5+1], cf[k*5+2]};
    naa[k] = (v2f){-cf[k*5+3], -cf[k*5+4]};
  }
}

__device__ __forceinline__ float cascade_step(float x, float* b0, v2f* bb, v2f* naa, v2f* st) {
  #pragma unroll
  for (int k = 0; k < 6; k++) {
    float y  = fmaf(b0[k], x, st[k].x);
    v2f upd  = __builtin_elementwise_fma(bb[k], (v2f){x, x}, (v2f){st[k].y, 0.f});
    st[k]    = __builtin_elementwise_fma(naa[k], (v2f){y, y}, upd);
    x = y;
  }
  return x;
}

// phase 1: zero-init chunk finals
__global__ __launch_bounds__(64) void k_phase1(const float* __restrict__ tracks,
                                               float* __restrict__ ws) {
  int j = blockIdx.x, n = threadIdx.x;
  float b0[6]; v2f bb[6], naa[6];
  load_coefs(ws + OFF_COEF + n*32, b0, bb, naa);
  v2f st[6];
  #pragma unroll
  for (int k = 0; k < 6; k++) st[k] = (v2f){0.f, 0.f};
  const float4* xp = (const float4*)(tracks + (size_t)n*S_LEN + (size_t)j*LCH);
  for (int i4 = 0; i4 < LCH/4; ++i4) {
    float4 xq = xp[i4];
    float xs[4] = {xq.x, xq.y, xq.z, xq.w};
    #pragma unroll
    for (int u = 0; u < 4; u++) (void)cascade_step(xs[u], b0, bb, naa, st);
  }
  float* f = ws + OFF_F + (size_t)n*(CCH*12) + (size_t)j*12;
  #pragma unroll
  for (int k = 0; k < 6; k++) { f[2*k] = st[k].x; f[2*k+1] = st[k].y; }
}

// serial scan of chunk-boundary states: z_{j+1} = M z_j + f_j
__global__ __launch_bounds__(64) void k_scanz(float* __restrict__ ws) {
  int n = threadIdx.x;
  float M[144];
  #pragma unroll
  for (int i = 0; i < 144; i++) M[i] = ws[OFF_M + (size_t)n*144 + i];
  float z[12];
  #pragma unroll
  for (int r = 0; r < 12; r++) z[r] = 0.f;
  const float* fb = ws + OFF_F + (size_t)n*(CCH*12);
  float*       zb = ws + OFF_Z + (size_t)n*(CCH*12);
  for (int j = 0; j < CCH; j++) {
    #pragma unroll
    for (int r = 0; r < 12; r++) zb[j*12+r] = z[r];
    float nz[12];
    #pragma unroll
    for (int r = 0; r < 12; r++) {
      float acc = fb[j*12+r];
      #pragma unroll
      for (int c = 0; c < 12; c++) acc = fmaf(M[r*12+c], z[c], acc);
      nz[r] = acc;
    }
    #pragma unroll
    for (int r = 0; r < 12; r++) z[r] = nz[r];
  }
}

// phase 3: correct-init EQ, compressor static gain g, pair-composed intercepts
__global__ __launch_bounds__(64) void k_phase3(const float* __restrict__ tracks,
                                               float* __restrict__ ws) {
  int j = blockIdx.x, n = threadIdx.x;
  float b0[6]; v2f bb[6], naa[6];
  load_coefs(ws + OFF_COEF + n*32, b0, bb, naa);
  const float* cm = ws + OFF_COMP + n*16;
  float a_a = cm[0], a_r = cm[1], kca = cm[2], kcr = cm[3];
  float T = cm[4], hK = cm[5], cg1 = cm[6], cg2 = cm[7];
  float u1 = cm[12], u2 = cm[13];
  v2f st[6];
  const float* zp = ws + OFF_Z + (size_t)n*(CCH*12) + (size_t)j*12;
  #pragma unroll
  for (int k = 0; k < 6; k++) st[k] = (v2f){zp[2*k], zp[2*k+1]};

  const float4* xp  = (const float4*)(tracks + (size_t)n*S_LEN + (size_t)j*LCH);
  float4* cpq = (float4*)(ws + OFF_CP) + (size_t)j*PPC*64;
  float2* yb  = (float2*)(ws + OFF_Y)  + (size_t)j*PPC*64;

  for (int i4 = 0; i4 < LCH/4; ++i4) {      // 2 pairs per iteration
    float4 xq = xp[i4];
    float xs[4] = {xq.x, xq.y, xq.z, xq.w};
    float ys[4], gv[4];
    #pragma unroll
    for (int u = 0; u < 4; u++) {
      float y = cascade_step(xs[u], b0, bb, naa, st);
      ys[u] = y;
      float v   = fabsf(y) + 1e-8f;
      float xdb = 6.020599913279624f * __log2f(v);   // 20*log10
      float d   = xdb - T;
      float dk  = d + hK;
      float g   = (d > hK) ? (cg1 * d) : (cg2 * dk * dk);
      g = (d < -hK) ? 0.f : g;
      gv[u] = g;
    }
    #pragma unroll
    for (int pp = 0; pp < 2; ++pp) {
      float ge = gv[2*pp], go = gv[2*pp+1];
      float C1 = kca * fmaf(a_a, ge, go);
      float C3 = kcr * fmaf(a_r, ge, go);
      float C2 = fmaxf(fmaf(u1, ge, kca*go), fmaf(u2, ge, kcr*go));
      int m = i4*2 + pp;
      cpq[(size_t)m*64 + n] = make_float4(C1, C2, C3, ge);
      yb [(size_t)m*64 + n] = make_float2(ys[2*pp], ys[2*pp+1]);
    }
  }
}

// ---------------------------------------------------------------------------
// serial max-affine smoother: ONE WAVE PER TRACK (64 blocks), register-
// prefetched group loads, v_readlane broadcast chain. Every lane computes the
// identical q sequence (C's are broadcast), so lane l captures q at m==l via
// select — no writelane needed.
__device__ __forceinline__ float rdlane(float v, int l) {
  return __int_as_float(__builtin_amdgcn_readlane(__float_as_int(v), l));
}

__global__ __launch_bounds__(64) void k_smooth(float* __restrict__ ws) {
  const int n = blockIdx.x;    // track
  const int l = threadIdx.x;   // lane
  const float* cm = ws + OFF_COMP + n*16;
  const float a_a = cm[0], a_r = cm[1];
  const float aa2 = a_a*a_a, aar = a_a*a_r, ar2 = a_r*a_r;
  const float4* __restrict__ cp = (const float4*)(ws + OFF_CP);
  float* __restrict__ qo = ws + OFF_QO + (size_t)n * NPAIR;

  float q = 0.f;
  // 2-deep register prefetch: each lane holds one pair's (C1,C2,C3,_)
  float4 buf0 = cp[(size_t)(0*64 + l)*64 + n];
  float4 buf1 = cp[(size_t)(1*64 + l)*64 + n];

  for (int g = 0; g < NPAIR/64; ++g) {
    float4 cur = buf0;
    buf0 = buf1;
    if (g + 2 < NPAIR/64)
      buf1 = cp[(size_t)((g+2)*64 + l)*64 + n];
    float qs = 0.f;
    #pragma unroll
    for (int m = 0; m < 64; ++m) {
      float C1 = rdlane(cur.x, m);
      float C2 = rdlane(cur.y, m);
      float C3 = rdlane(cur.z, m);
      q = fmaxf(fmaxf(fmaf(aa2, q, C1), fmaf(aar, q, C2)), fmaf(ar2, q, C3));
      qs = (l == m) ? q : qs;      // lane m captures q_m (all lanes agree on q)
    }
    qo[g*64 + l] = qs;
  }
}

// even-sample reconstruction + makeup gain + pan + 16-track mix
__global__ __launch_bounds__(256) void k_mix(const float* __restrict__ ws,
                                             float* __restrict__ out) {
  int b  = threadIdx.x & 3;
  int kk = blockIdx.x * 64 + (threadIdx.x >> 2);
  const float*  qo   = ws + OFF_QO;
  const float4* cp   = (const float4*)(ws + OFF_CP);
  const float2* yb   = (const float2*)(ws + OFF_Y);
  const float4* cmp4 = (const float4*)(ws + OFF_COMP);
  float accLe = 0, accRe = 0, accLo = 0, accRo = 0;
  int n0 = b * 16;
  int kp = (kk > 0) ? (kk - 1) : 0;
  #pragma unroll
  for (int t = 0; t < 16; t++) {
    int n = n0 + t;
    float4 ca = cmp4[n*4 + 0];              // a_a, a_r, kca, kcr
    float4 cc = cmp4[n*4 + 2];              // mka, sfac, cos, sin
    float qodd  = qo[(size_t)n*NPAIR + kk];
    float qprev = qo[(size_t)n*NPAIR + kp];
    qprev = (kk > 0) ? qprev : 0.f;
    float ge = cp[(size_t)kk*64 + n].w;
    float2 y2 = yb[(size_t)kk*64 + n];
    float qe  = fmaxf(fmaf(ca.x, qprev, ca.z*ge), fmaf(ca.y, qprev, ca.w*ge));
    float gle = exp2f(fmaf(-cc.y, qe,   cc.x));
    float glo = exp2f(fmaf(-cc.y, qodd, cc.x));
    float te = y2.x * gle, to = y2.y * glo;
    accLe = fmaf(cc.z, te, accLe); accRe = fmaf(cc.w, te, accRe);
    accLo = fmaf(cc.z, to, accLo); accRo = fmaf(cc.w, to, accRo);
  }
  float2* o = (float2*)out;
  o[(size_t)(b*2 + 0)*(S_LEN/2) + kk] = make_float2(accLe, accLo);
  o[(size_t)(b*2 + 1)*(S_LEN/2) + kk] = make_float2(accRe, accRo);
}

// ---------------------------------------------------------------------------
extern "C" void kernel_launch(void* const* d_in, const int* in_sizes, int n_in,
                              void* d_out, int out_size, void* d_ws, size_t ws_size,
                              hipStream_t stream) {
  const float* tracks = (const float*)d_in[0];
  const float* mp     = (const float*)d_in[1];
  float* ws  = (float*)d_ws;
  float* out = (float*)d_out;

  hipLaunchKernelGGL(k_setup,  dim3(1),    dim3(64),  0, stream, mp, ws);
  hipLaunchKernelGGL(k_matpow, dim3(64),   dim3(192), 0, stream, ws);
  hipLaunchKernelGGL(k_phase1, dim3(CCH),  dim3(64),  0, stream, tracks, ws);
  hipLaunchKernelGGL(k_scanz,  dim3(1),    dim3(64),  0, stream, ws);
  hipLaunchKernelGGL(k_phase3, dim3(CCH),  dim3(64),  0, stream, tracks, ws);
  hipLaunchKernelGGL(k_smooth, dim3(NTR),  dim3(64),  0, stream, ws);
  hipLaunchKernelGGL(k_mix,    dim3(NPAIR/64), dim3(256), 0, stream, ws, out);
}

// Round 4
// 1566.487 us; speedup vs baseline: 10.5161x; 1.0504x over previous
//
#include <hip/hip_runtime.h>
#include <math.h>

// ---------------------------------------------------------------------------
// AdvancedMixConsole: 64 tracks x 131072 samples.
//   gain -> 6 biquads (chunk-parallel linear recurrence, 12-dim state)
//        -> compressor: parallel static gain; serial smoother rewritten as
//           8-sample-composed max-affine chain (9 slopes aa^j ar^(8-j)),
//           one wave per track; intermediate samples reconstructed in
//           parallel from window-boundary q.
//        -> pan/mix (parallel, two-stage).
// ---------------------------------------------------------------------------

#define S_LEN 131072
#define NTR   64
#define CCH   256          // chunks
#define LCH   512          // samples per chunk
#define NSTEP 16384        // 8-sample windows per track
#define WPC   64           // windows per chunk
#define NGRP  256          // k_smooth groups of 64 windows

typedef float v2f __attribute__((ext_vector_type(2)));

// ws offsets in floats (total ~89.7 MB)
#define OFF_Y    0ull              // [131072][64]      EQ output y, sample-major
#define OFF_CI   8388608ull        // [NSTEP][64][12]   composed intercepts I[0..8] (+pad)
#define OFF_TV   8388608ull        // [131072][64]      tv = y*gain (ALIASES CI; used after k_smooth)
#define OFF_QB   20971520ull       // [NSTEP][64]       boundary q after each window
#define OFF_W    22020096ull       // [64][2]           cos/sin pan weights
#define OFF_COEF 22020224ull       // [64][32]          biquad coeffs
#define OFF_COMP 22022272ull       // [64][32]          compressor consts + 9 slopes
#define OFF_A    22024320ull       // [64][144]         cascade transition matrix
#define OFF_M    22033536ull       // [64][144]         A^LCH
#define OFF_F    22042752ull       // [64][CCH][12]     zero-init chunk finals
#define OFF_Z    22239360ull       // [64][CCH][12]     chunk init states

// ---------------------------------------------------------------------------
__global__ __launch_bounds__(64) void k_setup(const float* __restrict__ mp,
                                              float* __restrict__ ws) {
  int n = threadIdx.x;
  if (n >= NTR) return;
  const float* p = mp + n * 26;
  auto dn = [&](int i, double lo, double hi) { return (double)p[i] * (hi - lo) + lo; };

  double gain_db = dn(0, -24.0, 24.0);
  double glin = pow(10.0, gain_db / 20.0);
  const double nyq = 21050.0;  // 44100//2 - 1000

  double fg[6] = {dn(1,-24,24), dn(4,-24,24), dn(7,-24,24), dn(10,-24,24), dn(13,-24,24), dn(16,-24,24)};
  double ff[6] = {dn(2,20,2000), dn(5,80,2000), dn(8,2000,8000), dn(11,8000,12000), dn(14,12000,nyq), dn(17,6000,nyq)};
  double fq[6] = {dn(3,0.1,5), dn(6,0.1,5), dn(9,0.1,5), dn(12,0.1,5), dn(15,0.1,5), dn(18,0.1,5)};

  double B0[6], B1[6], B2[6], A1[6], A2[6];
  for (int k = 0; k < 6; k++) {
    double A  = pow(10.0, fg[k] / 40.0);
    double w0 = 2.0 * M_PI * ff[k] / 44100.0;
    double cw = cos(w0), sw = sin(w0);
    double al = sw / (2.0 * fq[k]);
    double sA = sqrt(A);
    double b0, b1, b2, a0, a1, a2;
    if (k == 0) {           // low shelf
      b0 = A*((A+1)-(A-1)*cw + 2*sA*al);
      b1 = 2*A*((A-1)-(A+1)*cw);
      b2 = A*((A+1)-(A-1)*cw - 2*sA*al);
      a0 = (A+1)+(A-1)*cw + 2*sA*al;
      a1 = -2*((A-1)+(A+1)*cw);
      a2 = (A+1)+(A-1)*cw - 2*sA*al;
    } else if (k == 5) {    // high shelf
      b0 = A*((A+1)+(A-1)*cw + 2*sA*al);
      b1 = -2*A*((A-1)+(A+1)*cw);
      b2 = A*((A+1)+(A-1)*cw - 2*sA*al);
      a0 = (A+1)-(A-1)*cw + 2*sA*al;
      a1 = 2*((A-1)-(A+1)*cw);
      a2 = (A+1)-(A-1)*cw - 2*sA*al;
    } else {                // peak
      b0 = 1 + al*A; b1 = -2*cw; b2 = 1 - al*A;
      a0 = 1 + al/A; a1 = -2*cw; a2 = 1 - al/A;
    }
    B0[k] = b0/a0; B1[k] = b1/a0; B2[k] = b2/a0; A1[k] = a1/a0; A2[k] = a2/a0;
  }
  // fold input gain into stage-0 numerator
  B0[0] *= glin; B1[0] *= glin; B2[0] *= glin;

  float* cf = ws + OFF_COEF + n * 32;
  for (int k = 0; k < 6; k++) {
    cf[k*5+0] = (float)B0[k]; cf[k*5+1] = (float)B1[k]; cf[k*5+2] = (float)B2[k];
    cf[k*5+3] = (float)A1[k]; cf[k*5+4] = (float)A2[k];
  }

  // compressor + pan constants
  double T = dn(19,-60,0), R = dn(20,1,10), atk = dn(21,1,1000), rel = dn(22,1,1000);
  double Kn = dn(23,3,24), mk = dn(24,0,24);
  double a_a = exp(-1.0 / (44100.0 * atk * 0.001));
  double a_r = exp(-1.0 / (44100.0 * rel * 0.001));
  double s   = (a_a < a_r) ? 1.0 : -1.0;     // q = s*p makes the recurrence pure-max
  double kca = s * (1.0 - a_a), kcr = s * (1.0 - a_r);
  double invR = 1.0 / R;
  const double K10 = 0.16609640474436813;    // log2(10)/20
  double theta = (double)p[25] * (M_PI / 2.0);

  float* cm = ws + OFF_COMP + n * 32;
  cm[0] = (float)a_a;  cm[1] = (float)a_r;  cm[2] = (float)kca; cm[3] = (float)kcr;
  cm[4] = (float)T;    cm[5] = (float)(Kn * 0.5);
  cm[6] = (float)(1.0 - invR);
  cm[7] = (float)((1.0 - invR) / (2.0 * Kn));
  cm[8] = (float)(mk * K10);   cm[9] = (float)(s * K10);
  cm[10] = (float)cos(theta);  cm[11] = (float)sin(theta);
  // 9 composed slopes aa^j * ar^(8-j), j = 0..8 (double-precision products)
  for (int j = 0; j <= 8; j++)
    cm[16+j] = (float)(pow(a_a, (double)j) * pow(a_r, (double)(8-j)));

  float* wp = ws + OFF_W + n*2;
  wp[0] = (float)cos(theta); wp[1] = (float)sin(theta);

  // homogeneous (x=0) cascade transition matrix, state = [s1_1,s2_1,...,s1_6,s2_6]
  double Am[12][12], yv[12], ny[12];
  for (int r = 0; r < 12; r++) { yv[r] = 0; for (int c = 0; c < 12; c++) Am[r][c] = 0; }
  for (int k = 0; k < 6; k++) {
    for (int c = 0; c < 12; c++) ny[c] = B0[k] * yv[c];
    ny[2*k] += 1.0;                                  // y_k = b0*y_{k-1} + s1_k
    for (int c = 0; c < 12; c++) Am[2*k][c]   = B1[k]*yv[c] - A1[k]*ny[c];
    Am[2*k][2*k+1] += 1.0;                           // + s2_k
    for (int c = 0; c < 12; c++) Am[2*k+1][c] = B2[k]*yv[c] - A2[k]*ny[c];
    for (int c = 0; c < 12; c++) yv[c] = ny[c];
  }
  float* Aw = ws + OFF_A + n * 144;
  for (int r = 0; r < 12; r++)
    for (int c = 0; c < 12; c++) Aw[r*12+c] = (float)Am[r][c];
}

// ---------------------------------------------------------------------------
__global__ __launch_bounds__(192) void k_matpow(float* __restrict__ ws) {
  __shared__ float As[144];
  int n = blockIdx.x, t = threadIdx.x;
  int r = t / 12, c = t % 12;
  if (t < 144) As[t] = ws[OFF_A + (size_t)n*144 + t];
  __syncthreads();
  for (int it = 0; it < 9; ++it) {   // A^(2^9) = A^LCH (LCH=512)
    float acc = 0.f;
    if (t < 144) {
      #pragma unroll
      for (int k = 0; k < 12; k++) acc += As[r*12+k] * As[k*12+c];
    }
    __syncthreads();
    if (t < 144) As[t] = acc;
    __syncthreads();
  }
  if (t < 144) ws[OFF_M + (size_t)n*144 + t] = As[t];
}

// ---------------------------------------------------------------------------
__device__ __forceinline__ void load_coefs(const float* cf, float* b0, v2f* bb, v2f* naa) {
  #pragma unroll
  for (int k = 0; k < 6; k++) {
    b0[k]  = cf[k*5+0];
    bb[k]  = (v2f){cf[k*5+1], cf[k*5+2]};
    naa[k] = (v2f){-cf[k*5+3], -cf[k*5+4]};
  }
}

__device__ __forceinline__ float cascade_step(float x, float* b0, v2f* bb, v2f* naa, v2f* st) {
  #pragma unroll
  for (int k = 0; k < 6; k++) {
    float y  = fmaf(b0[k], x, st[k].x);
    v2f upd  = __builtin_elementwise_fma(bb[k], (v2f){x, x}, (v2f){st[k].y, 0.f});
    st[k]    = __builtin_elementwise_fma(naa[k], (v2f){y, y}, upd);
    x = y;
  }
  return x;
}

// phase 1: zero-init chunk finals
__global__ __launch_bounds__(64) void k_phase1(const float* __restrict__ tracks,
                                               float* __restrict__ ws) {
  int j = blockIdx.x, n = threadIdx.x;
  float b0[6]; v2f bb[6], naa[6];
  load_coefs(ws + OFF_COEF + n*32, b0, bb, naa);
  v2f st[6];
  #pragma unroll
  for (int k = 0; k < 6; k++) st[k] = (v2f){0.f, 0.f};
  const float4* xp = (const float4*)(tracks + (size_t)n*S_LEN + (size_t)j*LCH);
  for (int i4 = 0; i4 < LCH/4; ++i4) {
    float4 xq = xp[i4];
    float xs[4] = {xq.x, xq.y, xq.z, xq.w};
    #pragma unroll
    for (int u = 0; u < 4; u++) (void)cascade_step(xs[u], b0, bb, naa, st);
  }
  float* f = ws + OFF_F + (size_t)n*(CCH*12) + (size_t)j*12;
  #pragma unroll
  for (int k = 0; k < 6; k++) { f[2*k] = st[k].x; f[2*k+1] = st[k].y; }
}

// serial scan of chunk-boundary states: z_{j+1} = M z_j + f_j
__global__ __launch_bounds__(64) void k_scanz(float* __restrict__ ws) {
  int n = threadIdx.x;
  float M[144];
  #pragma unroll
  for (int i = 0; i < 144; i++) M[i] = ws[OFF_M + (size_t)n*144 + i];
  float z[12];
  #pragma unroll
  for (int r = 0; r < 12; r++) z[r] = 0.f;
  const float* fb = ws + OFF_F + (size_t)n*(CCH*12);
  float*       zb = ws + OFF_Z + (size_t)n*(CCH*12);
  for (int j = 0; j < CCH; j++) {
    #pragma unroll
    for (int r = 0; r < 12; r++) zb[j*12+r] = z[r];
    float nz[12];
    #pragma unroll
    for (int r = 0; r < 12; r++) {
      float acc = fb[j*12+r];
      #pragma unroll
      for (int c = 0; c < 12; c++) acc = fmaf(M[r*12+c], z[c], acc);
      nz[r] = acc;
    }
    #pragma unroll
    for (int r = 0; r < 12; r++) z[r] = nz[r];
  }
}

// phase 3: correct-init EQ; per-sample static gain; per-8-sample-window
// composed max-affine intercepts I[0..8] (I[j] = best path with j attacks).
__global__ __launch_bounds__(64) void k_phase3(const float* __restrict__ tracks,
                                               float* __restrict__ ws) {
  int j = blockIdx.x, n = threadIdx.x;
  float b0[6]; v2f bb[6], naa[6];
  load_coefs(ws + OFF_COEF + n*32, b0, bb, naa);
  const float* cm = ws + OFF_COMP + n*32;
  float a_a = cm[0], a_r = cm[1], kca = cm[2], kcr = cm[3];
  float T = cm[4], hK = cm[5], cg1 = cm[6], cg2 = cm[7];
  v2f st[6];
  const float* zp = ws + OFF_Z + (size_t)n*(CCH*12) + (size_t)j*12;
  #pragma unroll
  for (int k = 0; k < 6; k++) st[k] = (v2f){zp[2*k], zp[2*k+1]};

  const float4* xp = (const float4*)(tracks + (size_t)n*S_LEN + (size_t)j*LCH);
  float* yb = ws + OFF_Y + (size_t)j*LCH*64 + n;                 // [sample][track]
  float* cw = ws + OFF_CI + ((size_t)(j*WPC)*64 + n)*12;         // [step][track][12]

  for (int w = 0; w < WPC; ++w) {
    float I[9];
    I[0] = 0.f;
    #pragma unroll
    for (int jj = 1; jj < 9; ++jj) I[jj] = -1e30f;
    #pragma unroll
    for (int i4 = 0; i4 < 2; ++i4) {
      float4 xq = xp[w*2 + i4];
      float xs[4] = {xq.x, xq.y, xq.z, xq.w};
      #pragma unroll
      for (int u = 0; u < 4; ++u) {
        const int i = i4*4 + u;
        float y = cascade_step(xs[u], b0, bb, naa, st);
        yb[(w*8 + i)*64] = y;
        float v   = fabsf(y) + 1e-8f;
        float xdb = 6.020599913279624f * __log2f(v);
        float d   = xdb - T;
        float dk  = d + hK;
        float gg  = (d > hK) ? (cg1*d) : (cg2*dk*dk);
        gg = (d < -hK) ? 0.f : gg;
        float ca = kca*gg, cr = kcr*gg;
        // compose one sample into the window map (descending j, in place)
        #pragma unroll
        for (int jj = 8; jj >= 0; --jj) {
          if (jj <= i+1) {
            float up = (jj > 0) ? fmaf(a_a, I[jj-1], ca) : -1e30f;
            I[jj] = fmaxf(up, fmaf(a_r, I[jj], cr));
          }
        }
      }
    }
    float4* cq = (float4*)(cw + (size_t)w*64*12);
    cq[0] = make_float4(I[0], I[1], I[2], I[3]);
    cq[1] = make_float4(I[4], I[5], I[6], I[7]);
    cq[2] = make_float4(I[8], 0.f, 0.f, 0.f);
  }
}

// ---------------------------------------------------------------------------
// serial max-affine smoother: one wave per track; one 9-term step per
// 8 samples. Lane l holds window (g*64+l)'s intercepts; chain broadcasts
// them via readlane; lane m captures its window's boundary q.
__device__ __forceinline__ float rdlane(float v, int l) {
  return __int_as_float(__builtin_amdgcn_readlane(__float_as_int(v), l));
}

__global__ __launch_bounds__(64) void k_smooth(float* __restrict__ ws) {
  const int n = blockIdx.x, l = threadIdx.x;
  const float* cm = ws + OFF_COMP + n*32;
  float S[9];
  #pragma unroll
  for (int j = 0; j < 9; ++j) S[j] = cm[16+j];
  const float4* __restrict__ cp = (const float4*)(ws + OFF_CI);
  float* __restrict__ qb = ws + OFF_QB;

  // prefetch 2 groups deep; step idx*3 float4s at [step][n]
  float4 a0 = cp[((size_t)(0*64 + l)*64 + n)*3 + 0];
  float4 a1 = cp[((size_t)(0*64 + l)*64 + n)*3 + 1];
  float4 a2 = cp[((size_t)(0*64 + l)*64 + n)*3 + 2];
  float4 b0 = cp[((size_t)(1*64 + l)*64 + n)*3 + 0];
  float4 b1 = cp[((size_t)(1*64 + l)*64 + n)*3 + 1];
  float4 b2 = cp[((size_t)(1*64 + l)*64 + n)*3 + 2];

  float q = 0.f;
  for (int g = 0; g < NGRP; ++g) {
    float4 c0 = a0, c1 = a1, c2 = a2;
    a0 = b0; a1 = b1; a2 = b2;
    if (g + 2 < NGRP) {
      const float4* nx = cp + ((size_t)((g+2)*64 + l)*64 + n)*3;
      b0 = nx[0]; b1 = nx[1]; b2 = nx[2];
    }
    float qs = 0.f;
    #pragma unroll
    for (int m = 0; m < 64; ++m) {
      float t0 = fmaf(S[0], q, rdlane(c0.x, m));
      float t1 = fmaf(S[1], q, rdlane(c0.y, m));
      float t2 = fmaf(S[2], q, rdlane(c0.z, m));
      float t3 = fmaf(S[3], q, rdlane(c0.w, m));
      float t4 = fmaf(S[4], q, rdlane(c1.x, m));
      float t5 = fmaf(S[5], q, rdlane(c1.y, m));
      float t6 = fmaf(S[6], q, rdlane(c1.z, m));
      float t7 = fmaf(S[7], q, rdlane(c1.w, m));
      float t8 = fmaf(S[8], q, rdlane(c2.x, m));
      float m0 = fmaxf(fmaxf(t0, t1), t2);     // -> v_max3
      float m1 = fmaxf(fmaxf(t3, t4), t5);
      float m2 = fmaxf(fmaxf(t6, t7), t8);
      q = fmaxf(fmaxf(m0, m1), m2);
      qs = (l == m) ? q : qs;
    }
    qb[(size_t)(g*64 + l)*64 + n] = qs;
  }
}

// tv = y * 10^((mk - p)/20): exact 8-step reconstruction from boundary q.
// lanes = tracks -> fully coalesced y/tv rows.
__global__ __launch_bounds__(256) void k_mix1(float* __restrict__ ws) {
  const int n  = threadIdx.x & 63;
  const int kk = blockIdx.x*4 + (threadIdx.x >> 6);
  const float* cm = ws + OFF_COMP + n*32;
  const float aa = cm[0], ar = cm[1], kca = cm[2], kcr = cm[3];
  const float T = cm[4], hK = cm[5], cg1 = cm[6], cg2 = cm[7];
  const float mkK = cm[8], sK = cm[9];
  const float* __restrict__ yb  = ws + OFF_Y;
  float* __restrict__       tvb = ws + OFF_TV;
  float q = (kk > 0) ? ws[OFF_QB + (size_t)(kk-1)*64 + n] : 0.f;
  #pragma unroll
  for (int i = 0; i < 8; ++i) {
    float y = yb[(size_t)(kk*8 + i)*64 + n];
    float v   = fabsf(y) + 1e-8f;
    float xdb = 6.020599913279624f * __log2f(v);
    float d   = xdb - T;
    float dk  = d + hK;
    float gg  = (d > hK) ? (cg1*d) : (cg2*dk*dk);
    gg = (d < -hK) ? 0.f : gg;
    q = fmaxf(fmaf(aa, q, kca*gg), fmaf(ar, q, kcr*gg));
    float sc = exp2f(fmaf(-sK, q, mkK));
    tvb[(size_t)(kk*8 + i)*64 + n] = y * sc;
  }
}

// 16-track pan reduction -> out[b][2][S]
__global__ __launch_bounds__(256) void k_mix2(const float* __restrict__ ws,
                                              float* __restrict__ out) {
  const int b = threadIdx.x & 3;
  const int s = blockIdx.x*64 + (threadIdx.x >> 2);
  const float* __restrict__ tvb = ws + OFF_TV;
  const float2* __restrict__ wp = (const float2*)(ws + OFF_W);
  float accL = 0.f, accR = 0.f;
  const int n0 = b*16;
  #pragma unroll
  for (int t = 0; t < 16; ++t) {
    float tv = tvb[(size_t)s*64 + n0 + t];
    float2 w2 = wp[n0 + t];
    accL = fmaf(w2.x, tv, accL);
    accR = fmaf(w2.y, tv, accR);
  }
  out[(size_t)(b*2 + 0)*S_LEN + s] = accL;
  out[(size_t)(b*2 + 1)*S_LEN + s] = accR;
}

// ---------------------------------------------------------------------------
extern "C" void kernel_launch(void* const* d_in, const int* in_sizes, int n_in,
                              void* d_out, int out_size, void* d_ws, size_t ws_size,
                              hipStream_t stream) {
  const float* tracks = (const float*)d_in[0];
  const float* mp     = (const float*)d_in[1];
  float* ws  = (float*)d_ws;
  float* out = (float*)d_out;

  hipLaunchKernelGGL(k_setup,  dim3(1),    dim3(64),  0, stream, mp, ws);
  hipLaunchKernelGGL(k_matpow, dim3(64),   dim3(192), 0, stream, ws);
  hipLaunchKernelGGL(k_phase1, dim3(CCH),  dim3(64),  0, stream, tracks, ws);
  hipLaunchKernelGGL(k_scanz,  dim3(1),    dim3(64),  0, stream, ws);
  hipLaunchKernelGGL(k_phase3, dim3(CCH),  dim3(64),  0, stream, tracks, ws);
  hipLaunchKernelGGL(k_smooth, dim3(NTR),  dim3(64),  0, stream, ws);
  hipLaunchKernelGGL(k_mix1,   dim3(NSTEP/4),  dim3(256), 0, stream, ws);
  hipLaunchKernelGGL(k_mix2,   dim3(S_LEN/64), dim3(256), 0, stream, ws, out);
}